// Round 6
// baseline (128.225 us; speedup 1.0000x reference)
//
#include <hip/hip_runtime.h>

#define NP    44
#define B     400000
#define B4    (B / 4)        // 100000 float4 groups per particle
#define BLK   256
#define GX    46             // blocks per particle: 46*44 = 2024 blocks ~ 7.9/CU
#define STRIDE (GX * BLK)    // 11776 float4 per sweep
#define FULL_ITERS 8         // 8*11776 = 94208 <= B4 always in-bounds

typedef float v4f __attribute__((ext_vector_type(4)));

// ---------------- kernel A: collapse 44 tiny MLPs to (gp, gn) pairs ----------
// Bias-free 1->4->8->4->1 ReLU MLP of a scalar is positively homogeneous:
//   y(x) = gp*x (x>=0),  gn*x (x<0) — exact.
__global__ __launch_bounds__(64) void collapse_kernel(
    const float* __restrict__ W1, const float* __restrict__ W2,
    const float* __restrict__ W3, const float* __restrict__ W4,
    float2* __restrict__ g)      // d_ws: (NP) float2
{
    const int l = threadIdx.x;
    if (l >= NP) return;
    const float* p1 = W1 + l * 4;
    const float* p2 = W2 + l * 32;
    const float* p3 = W3 + l * 32;
    const float* p4 = W4 + l * 4;

    float w1p[4], w1n[4];
#pragma unroll
    for (int k = 0; k < 4; ++k) {
        float w = p1[k];
        w1p[k] = fmaxf(w, 0.0f);
        w1n[k] = fminf(w, 0.0f);
    }
    float d2p[8], d2n[8];
#pragma unroll
    for (int i = 0; i < 8; ++i) {
        float ap = 0.0f, an = 0.0f;
#pragma unroll
        for (int k = 0; k < 4; ++k) {
            float w = p2[i * 4 + k];
            ap = fmaf(w, w1p[k], ap);
            an = fmaf(w, w1n[k], an);
        }
        d2p[i] = fmaxf(ap, 0.0f);
        d2n[i] = fminf(an, 0.0f);    // relu(x*c) = x*min(c,0) for x<0
    }
    float f3p[4], f3n[4];
#pragma unroll
    for (int j = 0; j < 4; ++j) {
        float ap = 0.0f, an = 0.0f;
#pragma unroll
        for (int i = 0; i < 8; ++i) {
            float w = p3[j * 8 + i];
            ap = fmaf(w, d2p[i], ap);
            an = fmaf(w, d2n[i], an);
        }
        f3p[j] = fmaxf(ap, 0.0f);
        f3n[j] = fminf(an, 0.0f);
    }
    float gp = 0.0f, gn = 0.0f;
#pragma unroll
    for (int j = 0; j < 4; ++j) {
        gp = fmaf(p4[j], f3p[j], gp);
        gn = fmaf(p4[j], f3n[j], gn);
    }
    g[l] = make_float2(gp, gn);
}

// ---------------- kernel B: persistent copy-shaped stream ----------------
__device__ __forceinline__ v4f scale4(v4f v, float gp, float gn) {
    v4f r;
    r.x = v.x * (v.x >= 0.0f ? gp : gn);
    r.y = v.y * (v.y >= 0.0f ? gp : gn);
    r.z = v.z * (v.z >= 0.0f ? gp : gn);
    r.w = v.w * (v.w >= 0.0f ? gp : gn);
    return r;
}

__global__ __launch_bounds__(BLK) void stream_kernel(
    const float* __restrict__ X,       // (NP, 1, B)
    const float2* __restrict__ g,      // (NP) collapsed gains
    float* __restrict__ out)           // (NP, 1, B)
{
    const int l = blockIdx.y;
    // wave-uniform address -> scalar load of (gp, gn)
    const float2 gg = g[l];
    const float gp = gg.x, gn = gg.y;

    const v4f* Xp = (const v4f*)(X + (size_t)l * B);
    v4f*       Op = (v4f*)(out + (size_t)l * B);

    const int base = blockIdx.x * BLK + threadIdx.x;

    // 8 always-in-bounds sweeps (copy-shaped loop: load_{i+1} issues behind store_i)
#pragma unroll
    for (int it = 0; it < FULL_ITERS; ++it) {
        const int idx = base + it * STRIDE;
        v4f v = Xp[idx];
        Op[idx] = scale4(v, gp, gn);
    }
    // guarded final sweep
    {
        const int idx = base + FULL_ITERS * STRIDE;
        if (idx < B4) {
            v4f v = Xp[idx];
            Op[idx] = scale4(v, gp, gn);
        }
    }
}

extern "C" void kernel_launch(void* const* d_in, const int* in_sizes, int n_in,
                              void* d_out, int out_size, void* d_ws, size_t ws_size,
                              hipStream_t stream) {
    const float* X  = (const float*)d_in[0];
    const float* W1 = (const float*)d_in[1];
    const float* W2 = (const float*)d_in[2];
    const float* W3 = (const float*)d_in[3];
    const float* W4 = (const float*)d_in[4];
    float* out = (float*)d_out;
    float2* g = (float2*)d_ws;         // 44 * 8 B scratch

    collapse_kernel<<<dim3(1), 64, 0, stream>>>(W1, W2, W3, W4, g);
    stream_kernel<<<dim3(GX, NP), BLK, 0, stream>>>(X, g, out);
}